// Round 1
// baseline (56.772 us; speedup 1.0000x reference)
//
#include <hip/hip_runtime.h>
#include <hip/hip_bf16.h>

// TT-Rec embedding bag, MI355X.
// P=(100,100,100), Q=(4,4,8), R=(1,32,32,1), D=128, B=4096, H=50, n=204800.
//
// Plan:
//   K1: scan lengths -> offsets[B+1]                        (ws)
//   K2: AB[pair=i1*100+i2][16][32] bf16 = a(4x32) @ b(32x128)   (ws, 10.24MB)
//       (pair == idx/100, since idx = i1*10000 + i2*100 + i3)
//   K3: Bfrag[i3] = c-row (32x8) prepacked in MFMA B-fragment order (51KB, ws)
//   K4: one wave per bag: 50x mfma_f32_16x16x32_bf16, acc in AGPRs, write 128 f32.

#define P0 100
#define P1 100
#define P2 100
#define Q0 4
#define Q1 4
#define Q2 8
#define R1c 32
#define R2c 32
#define DIM 128
#define NPAIR (P0 * P1)

typedef __attribute__((ext_vector_type(8))) short short8v;   // 8 bf16
typedef __attribute__((ext_vector_type(4))) float f32x4;

// ---------------- K1: exclusive scan of lengths ----------------
__global__ __launch_bounds__(1024) void scan_lengths(const int* __restrict__ lengths,
                                                     int B, int* __restrict__ offsets) {
    __shared__ int part[1024];
    int t = threadIdx.x;
    int per = (B + 1023) / 1024;
    int s = 0;
    for (int k = 0; k < per; ++k) {
        int i = t * per + k;
        s += (i < B) ? lengths[i] : 0;
    }
    part[t] = s;
    __syncthreads();
    // Hillis-Steele inclusive scan
    for (int d = 1; d < 1024; d <<= 1) {
        int v = (t >= d) ? part[t - d] : 0;
        __syncthreads();
        part[t] += v;
        __syncthreads();
    }
    int run = part[t] - s;   // exclusive prefix of this thread's chunk
    for (int k = 0; k < per; ++k) {
        int i = t * per + k;
        if (i < B) { offsets[i] = run; run += lengths[i]; }
    }
    if (t == 1023) offsets[B] = part[1023];
}

// ---------------- K2: build AB table (bf16) ----------------
// block = 128 threads, one (i1,i2) pair per block.
// thread t owns column col = t of b-row viewed as [r1=32][q2*r2=128];
// computes ab[a_][col] for a_=0..3, writes AB[pair][ (a_*4+b_)*32 + s ] where col=b_*32+s.
__global__ __launch_bounds__(128) void build_ab(const float* __restrict__ core0,
                                                const float* __restrict__ core1,
                                                __hip_bfloat16* __restrict__ ab) {
    int p12 = blockIdx.x;
    int i1 = p12 / P1;
    int i2 = p12 - i1 * P1;
    __shared__ float a_lds[Q0 * R1c];   // 128 floats
    int t = threadIdx.x;
    a_lds[t] = core0[i1 * (Q0 * R1c) + t];
    __syncthreads();

    const float* brow = core1 + (size_t)i2 * (R1c * Q1 * R2c);  // 4096 floats
    float acc0 = 0.f, acc1 = 0.f, acc2 = 0.f, acc3 = 0.f;
#pragma unroll
    for (int r = 0; r < R1c; ++r) {
        float bv = brow[r * (Q1 * R2c) + t];     // coalesced
        acc0 += a_lds[0 * R1c + r] * bv;          // uniform addr -> LDS broadcast
        acc1 += a_lds[1 * R1c + r] * bv;
        acc2 += a_lds[2 * R1c + r] * bv;
        acc3 += a_lds[3 * R1c + r] * bv;
    }
    __hip_bfloat16* o = ab + (size_t)p12 * 512;
    // element index = (a_*4 + b_)*32 + s = a_*128 + t   (t = b_*32+s)
    o[0 * 128 + t] = __float2bfloat16(acc0);
    o[1 * 128 + t] = __float2bfloat16(acc1);
    o[2 * 128 + t] = __float2bfloat16(acc2);
    o[3 * 128 + t] = __float2bfloat16(acc3);
}

// ---------------- K3: prepack c-rows into MFMA B-fragment order ----------------
// B operand of mfma_f32_16x16x32_bf16: lane l holds B[k=(l>>4)*8+j][col=l&15], j=0..7.
// We use cols 8..15 as duplicates of 0..7 (lanes l and l^8 read the same 16B -> coalesced
// broadcast, unique traffic 512B/row). Table element: i3*256 + (l>>4)*64 + (l&7)*8 + j.
__global__ __launch_bounds__(64) void build_bfrag(const float* __restrict__ core2,
                                                  __hip_bfloat16* __restrict__ bfrag) {
    int i3 = blockIdx.x;
    int l = threadIdx.x;
    if (l & 8) return;                    // lanes 8..15 etc. would duplicate writes
    int h = l >> 4, c3 = l & 7;
    const float* crow = core2 + (size_t)i3 * (R2c * Q2);
    __hip_bfloat16* o = bfrag + (size_t)i3 * 256 + h * 64 + c3 * 8;
#pragma unroll
    for (int j = 0; j < 8; ++j)
        o[j] = __float2bfloat16(crow[(h * 8 + j) * Q2 + c3]);
}

// ---------------- K4: bag pooling via MFMA ----------------
// 256 threads = 4 waves per block, one bag per wave.
__global__ __launch_bounds__(256) void bag_pool(const int* __restrict__ indices, int n,
                                                const int* __restrict__ offsets, int B,
                                                const short* __restrict__ ab,
                                                const short* __restrict__ bfrag,
                                                float* __restrict__ out) {
    int wave = threadIdx.x >> 6;
    int lane = threadIdx.x & 63;
    int bag = blockIdx.x * 4 + wave;
    if (bag >= B) return;

    int start = offsets[bag];
    int end = offsets[bag + 1];
    if (bag == B - 1 && end < n) end = n;   // jnp.repeat pads with last bag id

    // A fragment: lane l holds A[row=l&15][k=(l>>4)*8+j]; AB row-major [16][32] bf16.
    int aoff = (lane & 15) * 32 + (lane >> 4) * 8;           // bf16 elements
    int boff = (lane >> 4) * 64 + (lane & 7) * 8;            // bf16 elements

    f32x4 accA = {0.f, 0.f, 0.f, 0.f};
    f32x4 accB = {0.f, 0.f, 0.f, 0.f};

    int j = start;
    for (; j + 1 < end; j += 2) {
        int idx0 = indices[j];
        int idx1 = indices[j + 1];
        int p0 = idx0 / P2;  int i30 = idx0 - p0 * P2;
        int p1 = idx1 / P2;  int i31 = idx1 - p1 * P2;
        short8v a0 = *(const short8v*)(ab + (size_t)p0 * 512 + aoff);
        short8v b0 = *(const short8v*)(bfrag + (size_t)i30 * 256 + boff);
        short8v a1 = *(const short8v*)(ab + (size_t)p1 * 512 + aoff);
        short8v b1 = *(const short8v*)(bfrag + (size_t)i31 * 256 + boff);
        accA = __builtin_amdgcn_mfma_f32_16x16x32_bf16(a0, b0, accA, 0, 0, 0);
        accB = __builtin_amdgcn_mfma_f32_16x16x32_bf16(a1, b1, accB, 0, 0, 0);
    }
    if (j < end) {
        int idx0 = indices[j];
        int p0 = idx0 / P2;  int i30 = idx0 - p0 * P2;
        short8v a0 = *(const short8v*)(ab + (size_t)p0 * 512 + aoff);
        short8v b0 = *(const short8v*)(bfrag + (size_t)i30 * 256 + boff);
        accA = __builtin_amdgcn_mfma_f32_16x16x32_bf16(a0, b0, accA, 0, 0, 0);
    }
    f32x4 acc = accA + accB;

    // D layout: col = lane&15, row = (lane>>4)*4 + q. Useful cols 0..7.
    int col = lane & 15;
    if (col < 8) {
        int rb = (lane >> 4) * 4;
        float* orow = out + (size_t)bag * DIM;
#pragma unroll
        for (int q = 0; q < 4; ++q)
            orow[(rb + q) * 8 + col] = acc[q];   // d = m*8 + c3
    }
}

// ---------------- fallback (ws too small): direct VALU, equal-length bags ----------------
__global__ __launch_bounds__(128) void fallback_pool(const int* __restrict__ indices,
                                                     int n, int B,
                                                     const float* __restrict__ core0,
                                                     const float* __restrict__ core1,
                                                     const float* __restrict__ core2,
                                                     float* __restrict__ out) {
    int bag = blockIdx.x;
    int d = threadIdx.x;
    int m = d >> 3, c3 = d & 7;
    int a_ = m >> 2, b_ = m & 3;
    int H = n / B;
    float acc = 0.f;
    for (int j = bag * H; j < (bag + 1) * H; ++j) {
        int idx = indices[j];
        int i1 = idx / (P1 * P2);
        int rem = idx - i1 * (P1 * P2);
        int i2 = rem / P2;
        int i3 = rem - i2 * P2;
        const float* a = core0 + (size_t)i1 * 128;
        const float* b = core1 + (size_t)i2 * 4096;
        const float* c = core2 + (size_t)i3 * 256;
        float e = 0.f;
        for (int s = 0; s < 32; ++s) {
            float abv = 0.f;
            for (int r = 0; r < 32; ++r)
                abv += a[a_ * 32 + r] * b[r * 128 + b_ * 32 + s];
            e += abv * c[s * 8 + c3];
        }
        acc += e;
    }
    out[(size_t)bag * DIM + d] = acc;
}

extern "C" void kernel_launch(void* const* d_in, const int* in_sizes, int n_in,
                              void* d_out, int out_size, void* d_ws, size_t ws_size,
                              hipStream_t stream) {
    const int* indices = (const int*)d_in[0];
    const int* lengths = (const int*)d_in[1];
    const float* core0 = (const float*)d_in[2];
    const float* core1 = (const float*)d_in[3];
    const float* core2 = (const float*)d_in[4];
    float* out = (float*)d_out;
    int n = in_sizes[0];
    int B = in_sizes[1];

    const size_t OFF_OFFSETS = 0;                       // (B+1) ints
    const size_t OFF_BFRAG = 32768;                     // 100 * 512 B
    const size_t OFF_AB = 131072;                       // 10000 * 1024 B
    const size_t REQ = OFF_AB + (size_t)NPAIR * 512 * 2;

    if (ws_size >= REQ) {
        int* offsets = (int*)((char*)d_ws + OFF_OFFSETS);
        __hip_bfloat16* bfrag = (__hip_bfloat16*)((char*)d_ws + OFF_BFRAG);
        __hip_bfloat16* abt = (__hip_bfloat16*)((char*)d_ws + OFF_AB);

        scan_lengths<<<1, 1024, 0, stream>>>(lengths, B, offsets);
        build_ab<<<NPAIR, 128, 0, stream>>>(core0, core1, abt);
        build_bfrag<<<P2, 64, 0, stream>>>(core2, bfrag);
        bag_pool<<<(B + 3) / 4, 256, 0, stream>>>(indices, n, offsets, B,
                                                  (const short*)abt, (const short*)bfrag, out);
    } else {
        fallback_pool<<<B, 128, 0, stream>>>(indices, n, B, core0, core1, core2, out);
    }
}

// Round 2
// 43.654 us; speedup vs baseline: 1.3005x; 1.3005x over previous
//
#include <hip/hip_runtime.h>
#include <hip/hip_bf16.h>

// TT-Rec embedding bag, MI355X. R1 version.
// P=(100,100,100), Q=(4,4,8), R=(1,32,32,1), D=128, B=4096, H=50, n=204800.
//
//   K1 (prep, fused): block 0           -> scan lengths -> offsets[B+1]
//                     blocks 1..100     -> Bfrag[i3] prepack (MFMA B-frag order)
//                     blocks 101..10100 -> AB[pair][16][32] bf16 = a(4x32)@b(32x128)
//   K2 (bag_pool): one wave per bag; preload <=64 indices per chunk into lanes,
//                  shfl-broadcast byte offsets; 4-deep unrolled MFMA gather loop.

#define P0 100
#define P1 100
#define P2 100
#define Q0 4
#define Q1 4
#define Q2 8
#define DIM 128
#define NPAIR (P0 * P1)

typedef __attribute__((ext_vector_type(8))) short short8v;   // 8 bf16
typedef __attribute__((ext_vector_type(4))) float f32x4;

// ---------------- K1: fused prep ----------------
__global__ __launch_bounds__(128) void prep(const int* __restrict__ lengths, int B,
                                            const float* __restrict__ core0,
                                            const float* __restrict__ core1,
                                            const float* __restrict__ core2,
                                            int* __restrict__ offsets,
                                            __hip_bfloat16* __restrict__ bfrag,
                                            __hip_bfloat16* __restrict__ ab) {
    int bid = blockIdx.x;
    int t = threadIdx.x;
    if (bid == 0) {
        // ---- exclusive scan of lengths (single block, 128 threads) ----
        __shared__ int part[128];
        int per = (B + 127) / 128;
        int s = 0;
        for (int k = 0; k < per; ++k) {
            int i = t * per + k;
            s += (i < B) ? lengths[i] : 0;
        }
        part[t] = s;
        __syncthreads();
        for (int d = 1; d < 128; d <<= 1) {
            int v = (t >= d) ? part[t - d] : 0;
            __syncthreads();
            part[t] += v;
            __syncthreads();
        }
        int run = part[t] - s;
        for (int k = 0; k < per; ++k) {
            int i = t * per + k;
            if (i < B) { offsets[i] = run; run += lengths[i]; }
        }
        if (t == 127) offsets[B] = part[127];
    } else if (bid <= P2) {
        // ---- Bfrag prepack: lane l holds B[k=(l>>4)*8+j][col=l&15], cols 8..15 dup 0..7.
        // stored element: i3*256 + (l>>4)*64 + (l&7)*8 + j  (unduplicated, 512B/row)
        if (t < 64 && !(t & 8)) {
            int i3 = bid - 1;
            int h = t >> 4, c3 = t & 7;
            const float* crow = core2 + (size_t)i3 * (32 * Q2);
            __hip_bfloat16* o = bfrag + (size_t)i3 * 256 + h * 64 + c3 * 8;
#pragma unroll
            for (int j = 0; j < 8; ++j)
                o[j] = __float2bfloat16(crow[(h * 8 + j) * Q2 + c3]);
        }
    } else {
        // ---- AB build: one (i1,i2) pair per block ----
        int p12 = bid - 1 - P2;
        int i1 = p12 / P1;
        int i2 = p12 - i1 * P1;
        __shared__ float a_lds[128];
        a_lds[t] = core0[i1 * 128 + t];
        __syncthreads();
        const float* brow = core1 + (size_t)i2 * 4096;
        float acc0 = 0.f, acc1 = 0.f, acc2 = 0.f, acc3 = 0.f;
#pragma unroll
        for (int r = 0; r < 32; ++r) {
            float bv = brow[r * 128 + t];          // coalesced, core1 L2-resident
            acc0 += a_lds[r] * bv;                 // uniform addr -> LDS broadcast
            acc1 += a_lds[32 + r] * bv;
            acc2 += a_lds[64 + r] * bv;
            acc3 += a_lds[96 + r] * bv;
        }
        __hip_bfloat16* o = ab + (size_t)p12 * 512;
        o[t]       = __float2bfloat16(acc0);
        o[128 + t] = __float2bfloat16(acc1);
        o[256 + t] = __float2bfloat16(acc2);
        o[384 + t] = __float2bfloat16(acc3);
    }
}

// ---------------- K2: bag pooling via MFMA ----------------
// 256 threads = 4 waves per block, one bag per wave.
__global__ __launch_bounds__(256) void bag_pool(const int* __restrict__ indices, int n,
                                                const int* __restrict__ offsets, int B,
                                                const char* __restrict__ ab,
                                                const char* __restrict__ bfrag,
                                                float* __restrict__ out) {
    int wave = threadIdx.x >> 6;
    int lane = threadIdx.x & 63;
    int bag = blockIdx.x * 4 + wave;
    if (bag >= B) return;

    int start = offsets[bag];
    int end = offsets[bag + 1];
    if (bag == B - 1 && end < n) end = n;   // jnp.repeat pads with last bag id
    if (end > n) end = n;
    if (start > n) start = n;
    int cnt = end - start;

    // A fragment: lane l holds A[row=l&15][k=(l>>4)*8+j]; AB row-major [16][32] bf16.
    int aoff = (lane & 15) * 64 + (lane >> 4) * 16;     // bytes
    int boff = (lane >> 4) * 128 + (lane & 7) * 16;     // bytes

    f32x4 acc0 = {0.f, 0.f, 0.f, 0.f};
    f32x4 acc1 = {0.f, 0.f, 0.f, 0.f};
    f32x4 acc2 = {0.f, 0.f, 0.f, 0.f};
    f32x4 acc3 = {0.f, 0.f, 0.f, 0.f};

    for (int base = 0; base < cnt; base += 64) {
        int m = cnt - base;
        if (m > 64) m = 64;
        // lane j owns index (base+j): load once, decompose once.
        unsigned idx = 0;
        if (lane < m) idx = (unsigned)indices[start + base + lane];
        unsigned p = idx / 100u;                 // magic-mul, 2 VALU
        unsigned i3 = idx - p * 100u;
        int abo = (int)(p << 10);                // AB row byte offset
        int bfo = (int)(i3 << 9);                // bfrag row byte offset

        int j = 0;
        for (; j + 3 < m; j += 4) {
            int A0 = __shfl(abo, j),     B0 = __shfl(bfo, j);
            int A1 = __shfl(abo, j + 1), B1 = __shfl(bfo, j + 1);
            int A2 = __shfl(abo, j + 2), B2 = __shfl(bfo, j + 2);
            int A3 = __shfl(abo, j + 3), B3 = __shfl(bfo, j + 3);
            short8v a0 = *(const short8v*)(ab + A0 + aoff);
            short8v b0 = *(const short8v*)(bfrag + B0 + boff);
            short8v a1 = *(const short8v*)(ab + A1 + aoff);
            short8v b1 = *(const short8v*)(bfrag + B1 + boff);
            short8v a2 = *(const short8v*)(ab + A2 + aoff);
            short8v b2 = *(const short8v*)(bfrag + B2 + boff);
            short8v a3 = *(const short8v*)(ab + A3 + aoff);
            short8v b3 = *(const short8v*)(bfrag + B3 + boff);
            acc0 = __builtin_amdgcn_mfma_f32_16x16x32_bf16(a0, b0, acc0, 0, 0, 0);
            acc1 = __builtin_amdgcn_mfma_f32_16x16x32_bf16(a1, b1, acc1, 0, 0, 0);
            acc2 = __builtin_amdgcn_mfma_f32_16x16x32_bf16(a2, b2, acc2, 0, 0, 0);
            acc3 = __builtin_amdgcn_mfma_f32_16x16x32_bf16(a3, b3, acc3, 0, 0, 0);
        }
        for (; j < m; ++j) {
            int A0 = __shfl(abo, j), B0 = __shfl(bfo, j);
            short8v a0 = *(const short8v*)(ab + A0 + aoff);
            short8v b0 = *(const short8v*)(bfrag + B0 + boff);
            acc0 = __builtin_amdgcn_mfma_f32_16x16x32_bf16(a0, b0, acc0, 0, 0, 0);
        }
    }
    f32x4 acc = (acc0 + acc1) + (acc2 + acc3);

    // D layout: col = lane&15, row = (lane>>4)*4 + q; cols 0..7 useful (8..15 dup).
    int col = lane & 15;
    if (col < 8) {
        int rb = (lane >> 4) * 4;
        float* orow = out + (size_t)bag * DIM;
#pragma unroll
        for (int q = 0; q < 4; ++q)
            orow[(rb + q) * 8 + col] = acc[q];   // d = m*8 + c3
    }
}

// ---------------- fallback (ws too small): direct VALU, equal-length bags ----------------
__global__ __launch_bounds__(128) void fallback_pool(const int* __restrict__ indices,
                                                     int n, int B,
                                                     const float* __restrict__ core0,
                                                     const float* __restrict__ core1,
                                                     const float* __restrict__ core2,
                                                     float* __restrict__ out) {
    int bag = blockIdx.x;
    int d = threadIdx.x;
    int m = d >> 3, c3 = d & 7;
    int a_ = m >> 2, b_ = m & 3;
    int H = n / B;
    float acc = 0.f;
    for (int j = bag * H; j < (bag + 1) * H; ++j) {
        int idx = indices[j];
        int i1 = idx / (P1 * P2);
        int rem = idx - i1 * (P1 * P2);
        int i2 = rem / P2;
        int i3 = rem - i2 * P2;
        const float* a = core0 + (size_t)i1 * 128;
        const float* b = core1 + (size_t)i2 * 4096;
        const float* c = core2 + (size_t)i3 * 256;
        float e = 0.f;
        for (int s = 0; s < 32; ++s) {
            float abv = 0.f;
            for (int r = 0; r < 32; ++r)
                abv += a[a_ * 32 + r] * b[r * 128 + b_ * 32 + s];
            e += abv * c[s * 8 + c3];
        }
        acc += e;
    }
    out[(size_t)bag * DIM + d] = acc;
}

extern "C" void kernel_launch(void* const* d_in, const int* in_sizes, int n_in,
                              void* d_out, int out_size, void* d_ws, size_t ws_size,
                              hipStream_t stream) {
    const int* indices = (const int*)d_in[0];
    const int* lengths = (const int*)d_in[1];
    const float* core0 = (const float*)d_in[2];
    const float* core1 = (const float*)d_in[3];
    const float* core2 = (const float*)d_in[4];
    float* out = (float*)d_out;
    int n = in_sizes[0];
    int B = in_sizes[1];

    const size_t OFF_OFFSETS = 0;                       // (B+1) ints
    const size_t OFF_BFRAG = 32768;                     // 100 * 512 B
    const size_t OFF_AB = 131072;                       // 10000 * 1024 B
    const size_t REQ = OFF_AB + (size_t)NPAIR * 1024;

    if (ws_size >= REQ) {
        int* offsets = (int*)((char*)d_ws + OFF_OFFSETS);
        __hip_bfloat16* bfrag = (__hip_bfloat16*)((char*)d_ws + OFF_BFRAG);
        __hip_bfloat16* abt = (__hip_bfloat16*)((char*)d_ws + OFF_AB);

        prep<<<1 + P2 + NPAIR, 128, 0, stream>>>(lengths, B, core0, core1, core2,
                                                 offsets, bfrag, abt);
        bag_pool<<<(B + 3) / 4, 256, 0, stream>>>(indices, n, offsets, B,
                                                  (const char*)abt, (const char*)bfrag, out);
    } else {
        fallback_pool<<<B, 128, 0, stream>>>(indices, n, B, core0, core1, core2, out);
    }
}